// Round 13
// baseline (509.541 us; speedup 1.0000x reference)
//
#include <hip/hip_runtime.h>
#include <math.h>

#define N_NODES 100000
#define BSHIFT 8
#define BNODES 256
#define NB ((N_NODES + BNODES - 1) / BNODES)   // 391 buckets
#define CHUNK 8192

// ---- helpers -----------------------------------------------------------------

typedef float f32x2 __attribute__((ext_vector_type(2)));

__device__ __forceinline__ unsigned short f2bf(float x) {
    unsigned u = __float_as_uint(x);
    u += 0x7FFFu + ((u >> 16) & 1u);
    return (unsigned short)(u >> 16);
}
__device__ __forceinline__ unsigned pack2(float a, float b) {
    return (unsigned)f2bf(a) | ((unsigned)f2bf(b) << 16);
}
__device__ __forceinline__ float bflo(unsigned u) { return __uint_as_float(u << 16); }
__device__ __forceinline__ float bfhi(unsigned u) { return __uint_as_float(u & 0xFFFF0000u); }
__device__ __forceinline__ int nt_ld(const int* p) { return __builtin_nontemporal_load(p); }
__device__ __forceinline__ void nt_stf2(float* p, float a, float b) {
    f32x2 v; v.x = a; v.y = b;
    __builtin_nontemporal_store(v, (f32x2*)p);
}

// ---- pass 1: per-bucket edge counts ------------------------------------------

__global__ __launch_bounds__(256) void bucket_count(const int* __restrict__ dst,
                                                    int* __restrict__ bucketCount, int E) {
    __shared__ int hist[NB];
    for (int i = threadIdx.x; i < NB; i += 256) hist[i] = 0;
    __syncthreads();
    int i = blockIdx.x * blockDim.x + threadIdx.x;
    int stride = gridDim.x * blockDim.x;
    for (int e = i; e < E; e += stride)
        atomicAdd(&hist[nt_ld(dst + e) >> BSHIFT], 1);
    __syncthreads();
    for (int i2 = threadIdx.x; i2 < NB; i2 += 256) {
        int c = hist[i2];
        if (c) atomicAdd(&bucketCount[i2], c);
    }
}

// ---- pass 2: exclusive scan over NB bucket counts ----------------------------

__global__ __launch_bounds__(512) void bucket_scan(const int* __restrict__ bucketCount,
                                                   int* __restrict__ bucketOff,
                                                   int* __restrict__ bucketCursor, int E) {
    __shared__ int sh[512];
    int t = threadIdx.x;
    int v = (t < NB) ? bucketCount[t] : 0;
    sh[t] = v;
    __syncthreads();
    for (int d = 1; d < 512; d <<= 1) {
        int u = (t >= d) ? sh[t - d] : 0;
        __syncthreads();
        sh[t] += u;
        __syncthreads();
    }
    if (t < NB) { bucketOff[t] = sh[t] - v; bucketCursor[t] = sh[t] - v; }
    if (t == 0) bucketOff[NB] = E;
}

// ---- pass 3: block-grouped binning: rec = src | (dst_local << 17) ------------

__global__ __launch_bounds__(256) void bucket_fill(const int* __restrict__ src,
                                                   const int* __restrict__ dst,
                                                   int* __restrict__ bucketCursor,
                                                   unsigned int* __restrict__ binned, int E) {
    __shared__ int hist[NB];
    __shared__ int base[NB];
    __shared__ int lcur[NB];
    __shared__ unsigned int recs[CHUNK];
    __shared__ unsigned short bkt[CHUNK];
    int t = threadIdx.x;
    for (int i = t; i < NB; i += 256) { hist[i] = 0; lcur[i] = 0; }
    __syncthreads();
    int cbase = blockIdx.x * CHUNK;
#pragma unroll
    for (int j = 0; j < CHUNK / 256; ++j) {
        int slot = t + j * 256;
        int e = cbase + slot;
        if (e < E) {
            int s = nt_ld(src + e);
            int d = nt_ld(dst + e);
            recs[slot] = (unsigned)s | ((unsigned)(d & (BNODES - 1)) << 17);
            int b = d >> BSHIFT;
            bkt[slot] = (unsigned short)b;
            atomicAdd(&hist[b], 1);
        } else {
            bkt[slot] = 0xFFFF;
        }
    }
    __syncthreads();
    for (int i = t; i < NB; i += 256) {
        int c = hist[i];
        base[i] = c ? atomicAdd(&bucketCursor[i], c) : 0;
    }
    __syncthreads();
#pragma unroll
    for (int j = 0; j < CHUNK / 256; ++j) {
        int slot = t + j * 256;
        unsigned short b = bkt[slot];
        if (b != 0xFFFF) {
            int pos = base[b] + atomicAdd(&lcur[b], 1);
            binned[pos] = recs[slot];
        }
    }
}

// ---- pass 4 (fused): per-node offsets + dinv + node-sorted srcs --------------

__global__ __launch_bounds__(256) void node_off_sort(const unsigned int* __restrict__ binned,
                                                     const int* __restrict__ bucketOff,
                                                     int* __restrict__ off,
                                                     float* __restrict__ dinv,
                                                     int* __restrict__ srcs, int n, int E) {
    __shared__ int hist[BNODES];
    __shared__ int sh[BNODES];
    __shared__ int lcur[BNODES];
    int t = threadIdx.x;
    int b = blockIdx.x;
    hist[t] = 0;
    __syncthreads();
    int rb = bucketOff[b], re = bucketOff[b + 1];
    for (int e = rb + t; e < re; e += 256)
        atomicAdd(&hist[(binned[e] >> 17) & 255], 1);
    __syncthreads();
    int v = hist[t];
    sh[t] = v;
    __syncthreads();
    for (int d = 1; d < 256; d <<= 1) {
        int u = (t >= d) ? sh[t - d] : 0;
        __syncthreads();
        sh[t] += u;
        __syncthreads();
    }
    int base = rb + sh[t] - v;
    lcur[t] = base;
    int g = b * BNODES + t;
    if (g < n) {
        off[g] = base;
        dinv[g] = rsqrtf((float)v + 1.0f);   // +1 = self-loop
    }
    if (b == NB - 1 && t == 0) off[n] = E;
    __syncthreads();
    for (int e = rb + t; e < re; e += 256) {
        unsigned int r = binned[e];
        int pos = atomicAdd(&lcur[(r >> 17) & 255], 1);
        srcs[pos] = (int)(r & 0x1FFFF);
    }
}

// ---- pack x scaled by dinv, split: xa feats 0-15 (8 u32), xb 16-33 (9 u32) ---

__global__ void x_pack(const float* __restrict__ x, const float* __restrict__ dinv,
                       unsigned* __restrict__ xa, unsigned* __restrict__ xb, int n) {
    int i = blockIdx.x * blockDim.x + threadIdx.x;
    if (i >= n) return;
    float dv = dinv[i];
    const float2* xr = (const float2*)(x + (size_t)i * 34);
    unsigned* oa = xa + (size_t)i * 8;
#pragma unroll
    for (int j = 0; j < 8; ++j) { float2 v = xr[j]; oa[j] = pack2(dv * v.x, dv * v.y); }
    unsigned* ob = xb + (size_t)i * 9;
#pragma unroll
    for (int j = 0; j < 9; ++j) { float2 v = xr[8 + j]; ob[j] = pack2(dv * v.x, dv * v.y); }
}

// ---- layer-1 aggregation pass A: feats 0-15 from L2-resident 3.2MB table -----
// 8 lanes per node; lane f handles feats 2f,2f+1.

__global__ __launch_bounds__(256) void gather_xa(const int* __restrict__ off,
        const int* __restrict__ srcs, const unsigned* __restrict__ xa,
        const float* __restrict__ dinv, float* __restrict__ aggx, int n) {
    int g = blockIdx.x * 32 + (threadIdx.x >> 3);
    int f = threadIdx.x & 7;
    if (g >= n) return;
    int rb = off[g], re = off[g + 1];
    unsigned ug = xa[(size_t)g * 8 + f];
    float a0 = bflo(ug), a1 = bfhi(ug);
    int e = rb;
    for (; e + 8 <= re; e += 8) {
        int s0 = nt_ld(srcs + e),     s1 = nt_ld(srcs + e + 1);
        int s2 = nt_ld(srcs + e + 2), s3 = nt_ld(srcs + e + 3);
        int s4 = nt_ld(srcs + e + 4), s5 = nt_ld(srcs + e + 5);
        int s6 = nt_ld(srcs + e + 6), s7 = nt_ld(srcs + e + 7);
        unsigned u0 = xa[(size_t)s0 * 8 + f], u1 = xa[(size_t)s1 * 8 + f];
        unsigned u2 = xa[(size_t)s2 * 8 + f], u3 = xa[(size_t)s3 * 8 + f];
        unsigned u4 = xa[(size_t)s4 * 8 + f], u5 = xa[(size_t)s5 * 8 + f];
        unsigned u6 = xa[(size_t)s6 * 8 + f], u7 = xa[(size_t)s7 * 8 + f];
        a0 += bflo(u0); a1 += bfhi(u0); a0 += bflo(u1); a1 += bfhi(u1);
        a0 += bflo(u2); a1 += bfhi(u2); a0 += bflo(u3); a1 += bfhi(u3);
        a0 += bflo(u4); a1 += bfhi(u4); a0 += bflo(u5); a1 += bfhi(u5);
        a0 += bflo(u6); a1 += bfhi(u6); a0 += bflo(u7); a1 += bfhi(u7);
    }
    for (; e < re; ++e) {
        int s = nt_ld(srcs + e);
        unsigned u = xa[(size_t)s * 8 + f];
        a0 += bflo(u); a1 += bfhi(u);
    }
    float dv = dinv[g];
    nt_stf2(aggx + (size_t)g * 34 + 2 * f, dv * a0, dv * a1);
}

// ---- layer-1 aggregation pass B: feats 16-33 (9 u32/node; lane 0 tail) -------

__global__ __launch_bounds__(256) void gather_xb(const int* __restrict__ off,
        const int* __restrict__ srcs, const unsigned* __restrict__ xb,
        const float* __restrict__ dinv, float* __restrict__ aggx, int n) {
    int g = blockIdx.x * 32 + (threadIdx.x >> 3);
    int f = threadIdx.x & 7;
    if (g >= n) return;
    int rb = off[g], re = off[g + 1];
    unsigned ug = xb[(size_t)g * 9 + f];
    float a0 = bflo(ug), a1 = bfhi(ug);
    float a2 = 0.f, a3 = 0.f;
    if (f == 0) { unsigned tt = xb[(size_t)g * 9 + 8]; a2 = bflo(tt); a3 = bfhi(tt); }
    int e = rb;
    for (; e + 8 <= re; e += 8) {
        int s0 = nt_ld(srcs + e),     s1 = nt_ld(srcs + e + 1);
        int s2 = nt_ld(srcs + e + 2), s3 = nt_ld(srcs + e + 3);
        int s4 = nt_ld(srcs + e + 4), s5 = nt_ld(srcs + e + 5);
        int s6 = nt_ld(srcs + e + 6), s7 = nt_ld(srcs + e + 7);
        unsigned u0 = xb[(size_t)s0 * 9 + f], u1 = xb[(size_t)s1 * 9 + f];
        unsigned u2 = xb[(size_t)s2 * 9 + f], u3 = xb[(size_t)s3 * 9 + f];
        unsigned u4 = xb[(size_t)s4 * 9 + f], u5 = xb[(size_t)s5 * 9 + f];
        unsigned u6 = xb[(size_t)s6 * 9 + f], u7 = xb[(size_t)s7 * 9 + f];
        a0 += bflo(u0); a1 += bfhi(u0); a0 += bflo(u1); a1 += bfhi(u1);
        a0 += bflo(u2); a1 += bfhi(u2); a0 += bflo(u3); a1 += bfhi(u3);
        a0 += bflo(u4); a1 += bfhi(u4); a0 += bflo(u5); a1 += bfhi(u5);
        a0 += bflo(u6); a1 += bfhi(u6); a0 += bflo(u7); a1 += bfhi(u7);
        if (f == 0) {
            unsigned t0 = xb[(size_t)s0 * 9 + 8], t1 = xb[(size_t)s1 * 9 + 8];
            unsigned t2 = xb[(size_t)s2 * 9 + 8], t3 = xb[(size_t)s3 * 9 + 8];
            unsigned t4 = xb[(size_t)s4 * 9 + 8], t5 = xb[(size_t)s5 * 9 + 8];
            unsigned t6 = xb[(size_t)s6 * 9 + 8], t7 = xb[(size_t)s7 * 9 + 8];
            a2 += bflo(t0); a3 += bfhi(t0); a2 += bflo(t1); a3 += bfhi(t1);
            a2 += bflo(t2); a3 += bfhi(t2); a2 += bflo(t3); a3 += bfhi(t3);
            a2 += bflo(t4); a3 += bfhi(t4); a2 += bflo(t5); a3 += bfhi(t5);
            a2 += bflo(t6); a3 += bfhi(t6); a2 += bflo(t7); a3 += bfhi(t7);
        }
    }
    for (; e < re; ++e) {
        int s = nt_ld(srcs + e);
        unsigned u = xb[(size_t)s * 9 + f];
        a0 += bflo(u); a1 += bfhi(u);
        if (f == 0) { unsigned tt = xb[(size_t)s * 9 + 8]; a2 += bflo(tt); a3 += bfhi(tt); }
    }
    float dv = dinv[g];
    nt_stf2(aggx + (size_t)g * 34 + 16 + 2 * f, dv * a0, dv * a1);
    if (f == 0) nt_stf2(aggx + (size_t)g * 34 + 32, dv * a2, dv * a3);
}

// ---- fused layers 1+2 dense: writes split l2a (pairs 0-7) / l2b (8-15) -------

#define G12_BLOCKS 2048

__global__ __launch_bounds__(256) void gemm12(const float* __restrict__ aggx,
        const float* __restrict__ W1, const float* __restrict__ b1,
        const float* __restrict__ W2, const float* __restrict__ dinv,
        unsigned* __restrict__ l2a, unsigned* __restrict__ l2b, int n) {
    __shared__ float sW1t[64 * 34];
    __shared__ float sW2[64 * 32];
    __shared__ float sh1[16][64];
    for (int i = threadIdx.x; i < 34 * 64; i += 256) {
        int k = i >> 6, j = i & 63;
        sW1t[j * 34 + k] = W1[i];
    }
    for (int i = threadIdx.x; i < 64 * 32; i += 256) sW2[i] = W2[i];
    __syncthreads();
    int j  = threadIdx.x & 63;
    int rq = threadIdx.x >> 6;
    int p  = threadIdx.x & 15;
    int r2 = threadIdx.x >> 4;
    float bj = b1[j];
    const float2* w1v = (const float2*)(sW1t + j * 34);
    const float2* w2v = (const float2*)sW2;
    for (int base = blockIdx.x * 16; base < n; base += G12_BLOCKS * 16) {
#pragma unroll
        for (int q = 0; q < 4; ++q) {
            int r = rq * 4 + q;
            int row = base + r;
            float h1v = 0.f;
            if (row < n) {
                const float2* hr = (const float2*)(aggx + (size_t)row * 34);
                float acc = 0.f;
#pragma unroll
                for (int k2 = 0; k2 < 17; ++k2) {
                    float2 wv = w1v[k2];
                    float2 hv = hr[k2];
                    acc = fmaf(hv.x, wv.x, acc);
                    acc = fmaf(hv.y, wv.y, acc);
                }
                h1v = tanhf(acc + bj);
            }
            sh1[r][j] = h1v;
        }
        __syncthreads();
        {
            int row = base + r2;
            if (row < n) {
                const float2* sh1v = (const float2*)&sh1[r2][0];
                float a0 = 0.f, a1 = 0.f;
#pragma unroll
                for (int k2 = 0; k2 < 32; ++k2) {
                    float2 h = sh1v[k2];
                    float2 wa = w2v[(2 * k2) * 16 + p];
                    float2 wb = w2v[(2 * k2 + 1) * 16 + p];
                    a0 = fmaf(h.x, wa.x, a0); a1 = fmaf(h.x, wa.y, a1);
                    a0 = fmaf(h.y, wb.x, a0); a1 = fmaf(h.y, wb.y, a1);
                }
                float dv = dinv[row];
                unsigned pk = pack2(dv * a0, dv * a1);
                if (p < 8) l2a[(size_t)row * 8 + p] = pk;
                else       l2b[(size_t)row * 8 + (p - 8)] = pk;
            }
        }
        __syncthreads();
    }
}

// ---- layer-2 gather pass A: feats 0-15 -> tanh'd h2a (bf16) ------------------

__global__ __launch_bounds__(256) void gather2a(const int* __restrict__ off,
        const int* __restrict__ srcs, const unsigned* __restrict__ l2a,
        const float* __restrict__ dinv, const float* __restrict__ b2,
        unsigned* __restrict__ h2a, int n) {
    int g = blockIdx.x * 32 + (threadIdx.x >> 3);
    int f = threadIdx.x & 7;
    if (g >= n) return;
    int rb = off[g], re = off[g + 1];
    unsigned ug = l2a[(size_t)g * 8 + f];
    float a0 = bflo(ug), a1 = bfhi(ug);
    int e = rb;
    for (; e + 8 <= re; e += 8) {
        int s0 = nt_ld(srcs + e),     s1 = nt_ld(srcs + e + 1);
        int s2 = nt_ld(srcs + e + 2), s3 = nt_ld(srcs + e + 3);
        int s4 = nt_ld(srcs + e + 4), s5 = nt_ld(srcs + e + 5);
        int s6 = nt_ld(srcs + e + 6), s7 = nt_ld(srcs + e + 7);
        unsigned u0 = l2a[(size_t)s0 * 8 + f], u1 = l2a[(size_t)s1 * 8 + f];
        unsigned u2 = l2a[(size_t)s2 * 8 + f], u3 = l2a[(size_t)s3 * 8 + f];
        unsigned u4 = l2a[(size_t)s4 * 8 + f], u5 = l2a[(size_t)s5 * 8 + f];
        unsigned u6 = l2a[(size_t)s6 * 8 + f], u7 = l2a[(size_t)s7 * 8 + f];
        a0 += bflo(u0); a1 += bfhi(u0); a0 += bflo(u1); a1 += bfhi(u1);
        a0 += bflo(u2); a1 += bfhi(u2); a0 += bflo(u3); a1 += bfhi(u3);
        a0 += bflo(u4); a1 += bfhi(u4); a0 += bflo(u5); a1 += bfhi(u5);
        a0 += bflo(u6); a1 += bfhi(u6); a0 += bflo(u7); a1 += bfhi(u7);
    }
    for (; e < re; ++e) {
        int s = nt_ld(srcs + e);
        unsigned u = l2a[(size_t)s * 8 + f];
        a0 += bflo(u); a1 += bfhi(u);
    }
    float dv = dinv[g];
    float h0 = tanhf(fmaf(dv, a0, b2[2 * f]));
    float h1 = tanhf(fmaf(dv, a1, b2[2 * f + 1]));
    h2a[(size_t)g * 8 + f] = pack2(h0, h1);
}

// ---- layer-2 gather pass B: feats 16-31 + full W3 projection -> linh3 --------
// Transposed sW3t[o][k]: conflict-free broadcast reads.

__global__ __launch_bounds__(256) void gather2b(const int* __restrict__ off,
        const int* __restrict__ srcs, const unsigned* __restrict__ l2b,
        const unsigned* __restrict__ h2a, const float* __restrict__ dinv,
        const float* __restrict__ b2, const float* __restrict__ W3,
        unsigned* __restrict__ linh3, int n) {
    __shared__ float sW3t[16 * 32];
    for (int i = threadIdx.x; i < 32 * 16; i += 256) {
        int k = i >> 4, o = i & 15;
        sW3t[o * 32 + k] = W3[i];
    }
    __syncthreads();
    int g = blockIdx.x * 32 + (threadIdx.x >> 3);
    int f = threadIdx.x & 7;
    if (g >= n) return;
    int rb = off[g], re = off[g + 1];
    unsigned ug = l2b[(size_t)g * 8 + f];
    float a0 = bflo(ug), a1 = bfhi(ug);
    int e = rb;
    for (; e + 8 <= re; e += 8) {
        int s0 = nt_ld(srcs + e),     s1 = nt_ld(srcs + e + 1);
        int s2 = nt_ld(srcs + e + 2), s3 = nt_ld(srcs + e + 3);
        int s4 = nt_ld(srcs + e + 4), s5 = nt_ld(srcs + e + 5);
        int s6 = nt_ld(srcs + e + 6), s7 = nt_ld(srcs + e + 7);
        unsigned u0 = l2b[(size_t)s0 * 8 + f], u1 = l2b[(size_t)s1 * 8 + f];
        unsigned u2 = l2b[(size_t)s2 * 8 + f], u3 = l2b[(size_t)s3 * 8 + f];
        unsigned u4 = l2b[(size_t)s4 * 8 + f], u5 = l2b[(size_t)s5 * 8 + f];
        unsigned u6 = l2b[(size_t)s6 * 8 + f], u7 = l2b[(size_t)s7 * 8 + f];
        a0 += bflo(u0); a1 += bfhi(u0); a0 += bflo(u1); a1 += bfhi(u1);
        a0 += bflo(u2); a1 += bfhi(u2); a0 += bflo(u3); a1 += bfhi(u3);
        a0 += bflo(u4); a1 += bfhi(u4); a0 += bflo(u5); a1 += bfhi(u5);
        a0 += bflo(u6); a1 += bfhi(u6); a0 += bflo(u7); a1 += bfhi(u7);
    }
    for (; e < re; ++e) {
        int s = nt_ld(srcs + e);
        unsigned u = l2b[(size_t)s * 8 + f];
        a0 += bflo(u); a1 += bfhi(u);
    }
    float dv = dinv[g];
    float hh0 = tanhf(fmaf(dv, a0, b2[16 + 2 * f]));
    float hh1 = tanhf(fmaf(dv, a1, b2[17 + 2 * f]));
    unsigned ul = h2a[(size_t)g * 8 + f];
    float hl0 = bflo(ul), hl1 = bfhi(ul);
    float p[16];
#pragma unroll
    for (int o = 0; o < 16; ++o) {
        const float* wc = sW3t + o * 32;
        p[o] = hl0 * wc[2 * f] + hl1 * wc[2 * f + 1]
             + hh0 * wc[16 + 2 * f] + hh1 * wc[17 + 2 * f];
    }
#pragma unroll
    for (int m = 1; m <= 4; m <<= 1)
#pragma unroll
        for (int o = 0; o < 16; ++o) p[o] += __shfl_xor(p[o], m);
    linh3[(size_t)g * 8 + f] = pack2(dv * p[2 * f], dv * p[2 * f + 1]);
}

// ---- layer-3 gather + tanh + in-register W4 projection -> linh4 --------------
// Transposed sW4t[o][k]: conflict-free.

__global__ __launch_bounds__(256) void gather3_proj(const int* __restrict__ off,
        const int* __restrict__ srcs, const unsigned* __restrict__ linh3,
        const float* __restrict__ dinv, const float* __restrict__ b3,
        const float* __restrict__ W4, unsigned* __restrict__ linh4, int n) {
    __shared__ float sW4t[8 * 16];
    for (int i = threadIdx.x; i < 16 * 8; i += 256) {
        int k = i >> 3, o = i & 7;
        sW4t[o * 16 + k] = W4[i];
    }
    __syncthreads();
    int g = blockIdx.x * 32 + (threadIdx.x >> 3);
    int f = threadIdx.x & 7;
    if (g >= n) return;
    int rb = off[g], re = off[g + 1];
    unsigned ug = linh3[(size_t)g * 8 + f];
    float a0 = bflo(ug), a1 = bfhi(ug);
    int e = rb;
    for (; e + 8 <= re; e += 8) {
        int s0 = nt_ld(srcs + e),     s1 = nt_ld(srcs + e + 1);
        int s2 = nt_ld(srcs + e + 2), s3 = nt_ld(srcs + e + 3);
        int s4 = nt_ld(srcs + e + 4), s5 = nt_ld(srcs + e + 5);
        int s6 = nt_ld(srcs + e + 6), s7 = nt_ld(srcs + e + 7);
        unsigned u0 = linh3[(size_t)s0 * 8 + f], u1 = linh3[(size_t)s1 * 8 + f];
        unsigned u2 = linh3[(size_t)s2 * 8 + f], u3 = linh3[(size_t)s3 * 8 + f];
        unsigned u4 = linh3[(size_t)s4 * 8 + f], u5 = linh3[(size_t)s5 * 8 + f];
        unsigned u6 = linh3[(size_t)s6 * 8 + f], u7 = linh3[(size_t)s7 * 8 + f];
        a0 += bflo(u0); a1 += bfhi(u0); a0 += bflo(u1); a1 += bfhi(u1);
        a0 += bflo(u2); a1 += bfhi(u2); a0 += bflo(u3); a1 += bfhi(u3);
        a0 += bflo(u4); a1 += bfhi(u4); a0 += bflo(u5); a1 += bfhi(u5);
        a0 += bflo(u6); a1 += bfhi(u6); a0 += bflo(u7); a1 += bfhi(u7);
    }
    for (; e < re; ++e) {
        int s = nt_ld(srcs + e);
        unsigned u = linh3[(size_t)s * 8 + f];
        a0 += bflo(u); a1 += bfhi(u);
    }
    float dv = dinv[g];
    float h0 = tanhf(fmaf(dv, a0, b3[2 * f]));
    float h1 = tanhf(fmaf(dv, a1, b3[2 * f + 1]));
    float p[8];
#pragma unroll
    for (int o = 0; o < 8; ++o)
        p[o] = h0 * sW4t[o * 16 + 2 * f] + h1 * sW4t[o * 16 + 2 * f + 1];
#pragma unroll
    for (int m = 1; m <= 4; m <<= 1)
#pragma unroll
        for (int o = 0; o < 8; ++o) p[o] += __shfl_xor(p[o], m);
    if (f < 4) linh4[(size_t)g * 4 + f] = pack2(dv * p[2 * f], dv * p[2 * f + 1]);
}

// ---- layer-4 gather + tanh (writes hout) + fused classifier ------------------

__global__ __launch_bounds__(256) void gather4_cls(const int* __restrict__ off,
        const int* __restrict__ srcs, const unsigned* __restrict__ linh4,
        const float* __restrict__ dinv, const float* __restrict__ b4,
        float* __restrict__ hout, const float* __restrict__ Wc,
        const float* __restrict__ bc, float* __restrict__ out, int n) {
    int g = blockIdx.x * 64 + (threadIdx.x >> 2);
    int f = threadIdx.x & 3;
    if (g >= n) return;
    int rb = off[g], re = off[g + 1];
    unsigned ug = linh4[(size_t)g * 4 + f];
    float a0 = bflo(ug), a1 = bfhi(ug);
    int e = rb;
    for (; e + 8 <= re; e += 8) {
        int s0 = nt_ld(srcs + e),     s1 = nt_ld(srcs + e + 1);
        int s2 = nt_ld(srcs + e + 2), s3 = nt_ld(srcs + e + 3);
        int s4 = nt_ld(srcs + e + 4), s5 = nt_ld(srcs + e + 5);
        int s6 = nt_ld(srcs + e + 6), s7 = nt_ld(srcs + e + 7);
        unsigned u0 = linh4[(size_t)s0 * 4 + f], u1 = linh4[(size_t)s1 * 4 + f];
        unsigned u2 = linh4[(size_t)s2 * 4 + f], u3 = linh4[(size_t)s3 * 4 + f];
        unsigned u4 = linh4[(size_t)s4 * 4 + f], u5 = linh4[(size_t)s5 * 4 + f];
        unsigned u6 = linh4[(size_t)s6 * 4 + f], u7 = linh4[(size_t)s7 * 4 + f];
        a0 += bflo(u0); a1 += bfhi(u0); a0 += bflo(u1); a1 += bfhi(u1);
        a0 += bflo(u2); a1 += bfhi(u2); a0 += bflo(u3); a1 += bfhi(u3);
        a0 += bflo(u4); a1 += bfhi(u4); a0 += bflo(u5); a1 += bfhi(u5);
        a0 += bflo(u6); a1 += bfhi(u6); a0 += bflo(u7); a1 += bfhi(u7);
    }
    for (; e < re; ++e) {
        int s = nt_ld(srcs + e);
        unsigned u = linh4[(size_t)s * 4 + f];
        a0 += bflo(u); a1 += bfhi(u);
    }
    float dv = dinv[g];
    a0 = tanhf(fmaf(dv, a0, b4[2 * f]));
    a1 = tanhf(fmaf(dv, a1, b4[2 * f + 1]));
    *(float2*)(hout + (size_t)g * 8 + 2 * f) = make_float2(a0, a1);
    float p0 = a0 * Wc[4 * f]     + a1 * Wc[4 * f + 2];
    float p1 = a0 * Wc[4 * f + 1] + a1 * Wc[4 * f + 3];
    p0 += __shfl_xor(p0, 1); p1 += __shfl_xor(p1, 1);
    p0 += __shfl_xor(p0, 2); p1 += __shfl_xor(p1, 2);
    if (f == 0) {
        out[(size_t)g * 2]     = p0 + bc[0];
        out[(size_t)g * 2 + 1] = p1 + bc[1];
    }
}

// ---- launch ------------------------------------------------------------------

static inline char* alignp(char* p) {
    return (char*)(((uintptr_t)p + 15) & ~(uintptr_t)15);
}

extern "C" void kernel_launch(void* const* d_in, const int* in_sizes, int n_in,
                              void* d_out, int out_size, void* d_ws, size_t ws_size,
                              hipStream_t stream) {
    const float* x  = (const float*)d_in[0];
    const int*   ei = (const int*)d_in[1];
    const float* W1 = (const float*)d_in[2];  const float* b1 = (const float*)d_in[3];
    const float* W2 = (const float*)d_in[4];
    const float* b2 = (const float*)d_in[5];
    const float* W3 = (const float*)d_in[6];  const float* b3 = (const float*)d_in[7];
    const float* W4 = (const float*)d_in[8];  const float* b4 = (const float*)d_in[9];
    const float* Wc = (const float*)d_in[10]; const float* bc = (const float*)d_in[11];

    float* out  = (float*)d_out;                      // [N,2]
    float* hout = out + (size_t)2 * N_NODES;          // [N,8]

    const int n = N_NODES;
    const int E = in_sizes[1] / 2;
    const int* src = ei;
    const int* dst = ei + E;

    char* w = (char*)d_ws;
    float*        dinv         = (float*)w;        w = alignp(w + (size_t)n * 4);
    int*          bucketCount  = (int*)w;          w = alignp(w + (size_t)NB * 4);
    int*          bucketOff    = (int*)w;          w = alignp(w + (size_t)(NB + 1) * 4);
    int*          bucketCursor = (int*)w;          w = alignp(w + (size_t)NB * 4);
    int*          off          = (int*)w;          w = alignp(w + (size_t)(n + 1) * 4);
    unsigned int* binned       = (unsigned int*)w; w = alignp(w + (size_t)E * 4);
    int*          srcs         = (int*)w;          w = alignp(w + (size_t)E * 4);
    unsigned int* xa           = (unsigned int*)w; w = alignp(w + (size_t)n * 8 * 4);
    unsigned int* xb           = (unsigned int*)w; w = alignp(w + (size_t)n * 9 * 4);
    float*        aggx         = (float*)w;        w = alignp(w + (size_t)n * 34 * 4);
    unsigned int* l2a          = (unsigned int*)w; w = alignp(w + (size_t)n * 8 * 4);
    unsigned int* l2b          = (unsigned int*)w; w = alignp(w + (size_t)n * 8 * 4);
    unsigned int* h2a          = (unsigned int*)w; w = alignp(w + (size_t)n * 8 * 4);
    unsigned int* linh3        = (unsigned int*)w; w = alignp(w + (size_t)n * 8 * 4);
    unsigned int* linh4        = (unsigned int*)w; w = alignp(w + (size_t)n * 4 * 4);

    hipMemsetAsync(bucketCount, 0, NB * sizeof(int), stream);
    bucket_count<<<1024, 256, 0, stream>>>(dst, bucketCount, E);
    bucket_scan<<<1, 512, 0, stream>>>(bucketCount, bucketOff, bucketCursor, E);
    bucket_fill<<<(E + CHUNK - 1) / CHUNK, 256, 0, stream>>>(src, dst, bucketCursor, binned, E);
    node_off_sort<<<NB, 256, 0, stream>>>(binned, bucketOff, off, dinv, srcs, n, E);
    x_pack<<<(n + 255) / 256, 256, 0, stream>>>(x, dinv, xa, xb, n);

    // layer 1: two L2-resident gather passes, then fused 1+2 dense
    gather_xa<<<(n + 31) / 32, 256, 0, stream>>>(off, srcs, xa, dinv, aggx, n);
    gather_xb<<<(n + 31) / 32, 256, 0, stream>>>(off, srcs, xb, dinv, aggx, n);
    gemm12<<<G12_BLOCKS, 256, 0, stream>>>(aggx, W1, b1, W2, dinv, l2a, l2b, n);

    // layer 2: two L2-resident gather passes; pass B does the W3 projection
    gather2a<<<(n + 31) / 32, 256, 0, stream>>>(off, srcs, l2a, dinv, b2, h2a, n);
    gather2b<<<(n + 31) / 32, 256, 0, stream>>>(off, srcs, l2b, h2a, dinv, b2, W3, linh3, n);

    // layer 3 gather + projection to linh4
    gather3_proj<<<(n + 31) / 32, 256, 0, stream>>>(off, srcs, linh3, dinv, b3, W4, linh4, n);

    // layer 4 gather + classifier
    gather4_cls<<<(n + 63) / 64, 256, 0, stream>>>(off, srcs, linh4, dinv, b4, hout,
                                                   Wc, bc, out, n);
}

// Round 16
// 451.030 us; speedup vs baseline: 1.1297x; 1.1297x over previous
//
#include <hip/hip_runtime.h>
#include <math.h>

#define N_NODES 100000
#define BSHIFT 8
#define BNODES 256
#define NB ((N_NODES + BNODES - 1) / BNODES)   // 391 buckets
#define CHUNK 8192

// ---- helpers -----------------------------------------------------------------

typedef int i32x4 __attribute__((ext_vector_type(4)));

__device__ __forceinline__ unsigned short f2bf(float x) {
    unsigned u = __float_as_uint(x);
    u += 0x7FFFu + ((u >> 16) & 1u);
    return (unsigned short)(u >> 16);
}
__device__ __forceinline__ unsigned pack2(float a, float b) {
    return (unsigned)f2bf(a) | ((unsigned)f2bf(b) << 16);
}
__device__ __forceinline__ float bflo(unsigned u) { return __uint_as_float(u << 16); }
__device__ __forceinline__ float bfhi(unsigned u) { return __uint_as_float(u & 0xFFFF0000u); }
__device__ __forceinline__ int nt_ld(const int* p) { return __builtin_nontemporal_load(p); }
__device__ __forceinline__ i32x4 nt_ld4(const int* p) {
    return __builtin_nontemporal_load((const i32x4*)p);
}

// ---- pass 1: per-bucket edge counts ------------------------------------------

__global__ __launch_bounds__(256) void bucket_count(const int* __restrict__ dst,
                                                    int* __restrict__ bucketCount, int E) {
    __shared__ int hist[NB];
    for (int i = threadIdx.x; i < NB; i += 256) hist[i] = 0;
    __syncthreads();
    int i = blockIdx.x * blockDim.x + threadIdx.x;
    int stride = gridDim.x * blockDim.x;
    for (int e = i; e < E; e += stride)
        atomicAdd(&hist[nt_ld(dst + e) >> BSHIFT], 1);
    __syncthreads();
    for (int i2 = threadIdx.x; i2 < NB; i2 += 256) {
        int c = hist[i2];
        if (c) atomicAdd(&bucketCount[i2], c);
    }
}

// ---- pass 2: exclusive scan over NB bucket counts ----------------------------

__global__ __launch_bounds__(512) void bucket_scan(const int* __restrict__ bucketCount,
                                                   int* __restrict__ bucketOff,
                                                   int* __restrict__ bucketCursor, int E) {
    __shared__ int sh[512];
    int t = threadIdx.x;
    int v = (t < NB) ? bucketCount[t] : 0;
    sh[t] = v;
    __syncthreads();
    for (int d = 1; d < 512; d <<= 1) {
        int u = (t >= d) ? sh[t - d] : 0;
        __syncthreads();
        sh[t] += u;
        __syncthreads();
    }
    if (t < NB) { bucketOff[t] = sh[t] - v; bucketCursor[t] = sh[t] - v; }
    if (t == 0) bucketOff[NB] = E;
}

// ---- pass 3: block-grouped binning: rec = src | (dst_local << 17) ------------

__global__ __launch_bounds__(256) void bucket_fill(const int* __restrict__ src,
                                                   const int* __restrict__ dst,
                                                   int* __restrict__ bucketCursor,
                                                   unsigned int* __restrict__ binned, int E) {
    __shared__ int hist[NB];
    __shared__ int base[NB];
    __shared__ int lcur[NB];
    __shared__ unsigned int recs[CHUNK];
    __shared__ unsigned short bkt[CHUNK];
    int t = threadIdx.x;
    for (int i = t; i < NB; i += 256) { hist[i] = 0; lcur[i] = 0; }
    __syncthreads();
    int cbase = blockIdx.x * CHUNK;
#pragma unroll
    for (int j = 0; j < CHUNK / 256; ++j) {
        int slot = t + j * 256;
        int e = cbase + slot;
        if (e < E) {
            int s = nt_ld(src + e);
            int d = nt_ld(dst + e);
            recs[slot] = (unsigned)s | ((unsigned)(d & (BNODES - 1)) << 17);
            int b = d >> BSHIFT;
            bkt[slot] = (unsigned short)b;
            atomicAdd(&hist[b], 1);
        } else {
            bkt[slot] = 0xFFFF;
        }
    }
    __syncthreads();
    for (int i = t; i < NB; i += 256) {
        int c = hist[i];
        base[i] = c ? atomicAdd(&bucketCursor[i], c) : 0;
    }
    __syncthreads();
#pragma unroll
    for (int j = 0; j < CHUNK / 256; ++j) {
        int slot = t + j * 256;
        unsigned short b = bkt[slot];
        if (b != 0xFFFF) {
            int pos = base[b] + atomicAdd(&lcur[b], 1);
            binned[pos] = recs[slot];
        }
    }
}

// ---- pass 4 (fused): per-node offsets + dinv + node-sorted srcs --------------

__global__ __launch_bounds__(256) void node_off_sort(const unsigned int* __restrict__ binned,
                                                     const int* __restrict__ bucketOff,
                                                     int* __restrict__ off,
                                                     float* __restrict__ dinv,
                                                     int* __restrict__ srcs, int n, int E) {
    __shared__ int hist[BNODES];
    __shared__ int sh[BNODES];
    __shared__ int lcur[BNODES];
    int t = threadIdx.x;
    int b = blockIdx.x;
    hist[t] = 0;
    __syncthreads();
    int rb = bucketOff[b], re = bucketOff[b + 1];
    for (int e = rb + t; e < re; e += 256)
        atomicAdd(&hist[(binned[e] >> 17) & 255], 1);
    __syncthreads();
    int v = hist[t];
    sh[t] = v;
    __syncthreads();
    for (int d = 1; d < 256; d <<= 1) {
        int u = (t >= d) ? sh[t - d] : 0;
        __syncthreads();
        sh[t] += u;
        __syncthreads();
    }
    int base = rb + sh[t] - v;
    lcur[t] = base;
    int g = b * BNODES + t;
    if (g < n) {
        off[g] = base;
        dinv[g] = rsqrtf((float)v + 1.0f);   // +1 = self-loop
    }
    if (b == NB - 1 && t == 0) off[n] = E;
    __syncthreads();
    for (int e = rb + t; e < re; e += 256) {
        unsigned int r = binned[e];
        int pos = atomicAdd(&lcur[(r >> 17) & 255], 1);
        srcs[pos] = (int)(r & 0x1FFFF);
    }
}

// ---- pack x scaled by dinv: xm[i]=bf16(dinv[i]*x[i]) [16 u32], xt tail -------

__global__ void x_pack(const float* __restrict__ x, const float* __restrict__ dinv,
                       unsigned* __restrict__ xm, unsigned* __restrict__ xt, int n) {
    int i = blockIdx.x * blockDim.x + threadIdx.x;
    if (i >= n) return;
    float dv = dinv[i];
    const float2* xr = (const float2*)(x + (size_t)i * 34);
    unsigned* om = xm + (size_t)i * 16;
#pragma unroll
    for (int j = 0; j < 16; ++j) { float2 v = xr[j]; om[j] = pack2(dv * v.x, dv * v.y); }
    float2 v = xr[16];
    xt[i] = pack2(dv * v.x, dv * v.y);
}

// ---- layer-1 aggregation: aggx[g] = dinv[g] * (xm'[g] + sum_e xm'[src]) ------
// 16 lanes per node; 16-edge deep pipeline with i32x4 src loads.

__global__ __launch_bounds__(256) void gather_x_bf16(const int* __restrict__ off,
        const int* __restrict__ srcs, const unsigned* __restrict__ xm,
        const unsigned* __restrict__ xt, const float* __restrict__ dinv,
        float* __restrict__ aggx, int n) {
    int g = blockIdx.x * 16 + (threadIdx.x >> 4);
    int f = threadIdx.x & 15;
    if (g >= n) return;
    int rb = off[g], re = off[g + 1];
    unsigned ug = xm[(size_t)g * 16 + f];
    float a0 = bflo(ug), a1 = bfhi(ug);
    float a2 = 0.f, a3 = 0.f;
    if (f == 0) { unsigned tt = xt[g]; a2 = bflo(tt); a3 = bfhi(tt); }
    int e = rb;
    for (; e < re && (e & 3); ++e) {          // peel to 16B alignment
        int s = nt_ld(srcs + e);
        unsigned u = xm[(size_t)s * 16 + f];
        a0 += bflo(u); a1 += bfhi(u);
        if (f == 0) { unsigned tt = xt[s]; a2 += bflo(tt); a3 += bfhi(tt); }
    }
    for (; e + 16 <= re; e += 16) {
        i32x4 v0 = nt_ld4(srcs + e),     v1 = nt_ld4(srcs + e + 4);
        i32x4 v2 = nt_ld4(srcs + e + 8), v3 = nt_ld4(srcs + e + 12);
        int ss[16] = { v0[0], v0[1], v0[2], v0[3], v1[0], v1[1], v1[2], v1[3],
                       v2[0], v2[1], v2[2], v2[3], v3[0], v3[1], v3[2], v3[3] };
        unsigned uu[16];
#pragma unroll
        for (int q = 0; q < 16; ++q) uu[q] = xm[(size_t)ss[q] * 16 + f];
#pragma unroll
        for (int q = 0; q < 16; ++q) { a0 += bflo(uu[q]); a1 += bfhi(uu[q]); }
        if (f == 0) {
            unsigned tt[16];
#pragma unroll
            for (int q = 0; q < 16; ++q) tt[q] = xt[ss[q]];
#pragma unroll
            for (int q = 0; q < 16; ++q) { a2 += bflo(tt[q]); a3 += bfhi(tt[q]); }
        }
    }
    for (; e + 4 <= re; e += 4) {
        i32x4 v = nt_ld4(srcs + e);
        int ss[4] = { v[0], v[1], v[2], v[3] };
        unsigned uu[4];
#pragma unroll
        for (int q = 0; q < 4; ++q) uu[q] = xm[(size_t)ss[q] * 16 + f];
#pragma unroll
        for (int q = 0; q < 4; ++q) { a0 += bflo(uu[q]); a1 += bfhi(uu[q]); }
        if (f == 0) {
#pragma unroll
            for (int q = 0; q < 4; ++q) {
                unsigned tt = xt[ss[q]]; a2 += bflo(tt); a3 += bfhi(tt);
            }
        }
    }
    for (; e < re; ++e) {
        int s = nt_ld(srcs + e);
        unsigned u = xm[(size_t)s * 16 + f];
        a0 += bflo(u); a1 += bfhi(u);
        if (f == 0) { unsigned tt = xt[s]; a2 += bflo(tt); a3 += bfhi(tt); }
    }
    float dv = dinv[g];
    *(float2*)(aggx + (size_t)g * 34 + 2 * f) = make_float2(dv * a0, dv * a1);
    if (f == 0) *(float2*)(aggx + (size_t)g * 34 + 32) = make_float2(dv * a2, dv * a3);
}

// ---- fused layers 1+2 dense: linh2 = bf16(dinv * (tanh(aggx*W1+b1) * W2)) ----

#define G12_BLOCKS 2048

__global__ __launch_bounds__(256) void gemm12(const float* __restrict__ aggx,
        const float* __restrict__ W1, const float* __restrict__ b1,
        const float* __restrict__ W2, const float* __restrict__ dinv,
        unsigned* __restrict__ linh2, int n) {
    __shared__ float sW1t[64 * 34];
    __shared__ float sW2[64 * 32];
    __shared__ float sh1[16][64];
    for (int i = threadIdx.x; i < 34 * 64; i += 256) {
        int k = i >> 6, j = i & 63;
        sW1t[j * 34 + k] = W1[i];
    }
    for (int i = threadIdx.x; i < 64 * 32; i += 256) sW2[i] = W2[i];
    __syncthreads();
    int j  = threadIdx.x & 63;
    int rq = threadIdx.x >> 6;
    int p  = threadIdx.x & 15;
    int r2 = threadIdx.x >> 4;
    float bj = b1[j];
    const float2* w1v = (const float2*)(sW1t + j * 34);
    const float2* w2v = (const float2*)sW2;
    for (int base = blockIdx.x * 16; base < n; base += G12_BLOCKS * 16) {
#pragma unroll
        for (int q = 0; q < 4; ++q) {
            int r = rq * 4 + q;
            int row = base + r;
            float h1v = 0.f;
            if (row < n) {
                const float2* hr = (const float2*)(aggx + (size_t)row * 34);
                float acc = 0.f;
#pragma unroll
                for (int k2 = 0; k2 < 17; ++k2) {
                    float2 wv = w1v[k2];
                    float2 hv = hr[k2];
                    acc = fmaf(hv.x, wv.x, acc);
                    acc = fmaf(hv.y, wv.y, acc);
                }
                h1v = tanhf(acc + bj);
            }
            sh1[r][j] = h1v;
        }
        __syncthreads();
        {
            int row = base + r2;
            if (row < n) {
                const float2* sh1v = (const float2*)&sh1[r2][0];
                float a0 = 0.f, a1 = 0.f;
#pragma unroll
                for (int k2 = 0; k2 < 32; ++k2) {
                    float2 h = sh1v[k2];
                    float2 wa = w2v[(2 * k2) * 16 + p];
                    float2 wb = w2v[(2 * k2 + 1) * 16 + p];
                    a0 = fmaf(h.x, wa.x, a0); a1 = fmaf(h.x, wa.y, a1);
                    a0 = fmaf(h.y, wb.x, a0); a1 = fmaf(h.y, wb.y, a1);
                }
                float dv = dinv[row];
                linh2[(size_t)row * 16 + p] = pack2(dv * a0, dv * a1);
            }
        }
        __syncthreads();
    }
}

// ---- layer-2 gather + tanh + in-register W3 projection -> linh3 --------------
// 16 lanes per node; transposed sW3t (conflict-free); 16-deep pipeline.

__global__ __launch_bounds__(256) void gather2_proj(const int* __restrict__ off,
        const int* __restrict__ srcs, const unsigned* __restrict__ linh2,
        const float* __restrict__ dinv, const float* __restrict__ b2,
        const float* __restrict__ W3, unsigned* __restrict__ linh3, int n) {
    __shared__ float sW3t[16 * 32];
    for (int i = threadIdx.x; i < 32 * 16; i += 256) {
        int k = i >> 4, o = i & 15;
        sW3t[o * 32 + k] = W3[i];
    }
    __syncthreads();
    int g = blockIdx.x * 16 + (threadIdx.x >> 4);
    int f = threadIdx.x & 15;
    if (g >= n) return;
    int rb = off[g], re = off[g + 1];
    unsigned ug = linh2[(size_t)g * 16 + f];
    float a0 = bflo(ug), a1 = bfhi(ug);
    int e = rb;
    for (; e < re && (e & 3); ++e) {
        int s = nt_ld(srcs + e);
        unsigned u = linh2[(size_t)s * 16 + f];
        a0 += bflo(u); a1 += bfhi(u);
    }
    for (; e + 16 <= re; e += 16) {
        i32x4 v0 = nt_ld4(srcs + e),     v1 = nt_ld4(srcs + e + 4);
        i32x4 v2 = nt_ld4(srcs + e + 8), v3 = nt_ld4(srcs + e + 12);
        int ss[16] = { v0[0], v0[1], v0[2], v0[3], v1[0], v1[1], v1[2], v1[3],
                       v2[0], v2[1], v2[2], v2[3], v3[0], v3[1], v3[2], v3[3] };
        unsigned uu[16];
#pragma unroll
        for (int q = 0; q < 16; ++q) uu[q] = linh2[(size_t)ss[q] * 16 + f];
#pragma unroll
        for (int q = 0; q < 16; ++q) { a0 += bflo(uu[q]); a1 += bfhi(uu[q]); }
    }
    for (; e + 4 <= re; e += 4) {
        i32x4 v = nt_ld4(srcs + e);
        int ss[4] = { v[0], v[1], v[2], v[3] };
        unsigned uu[4];
#pragma unroll
        for (int q = 0; q < 4; ++q) uu[q] = linh2[(size_t)ss[q] * 16 + f];
#pragma unroll
        for (int q = 0; q < 4; ++q) { a0 += bflo(uu[q]); a1 += bfhi(uu[q]); }
    }
    for (; e < re; ++e) {
        int s = nt_ld(srcs + e);
        unsigned u = linh2[(size_t)s * 16 + f];
        a0 += bflo(u); a1 += bfhi(u);
    }
    float dv = dinv[g];
    float h0 = tanhf(fmaf(dv, a0, b2[2 * f]));
    float h1 = tanhf(fmaf(dv, a1, b2[2 * f + 1]));
    float p[16];
#pragma unroll
    for (int o = 0; o < 16; ++o)
        p[o] = h0 * sW3t[o * 32 + 2 * f] + h1 * sW3t[o * 32 + 2 * f + 1];
#pragma unroll
    for (int m = 1; m <= 8; m <<= 1)
#pragma unroll
        for (int o = 0; o < 16; ++o) p[o] += __shfl_xor(p[o], m);
    if (f < 8) linh3[(size_t)g * 8 + f] = pack2(dv * p[2 * f], dv * p[2 * f + 1]);
}

// ---- layer-3 gather + tanh + in-register W4 projection -> linh4 --------------
// 8 lanes per node; transposed sW4t; 16-deep pipeline.

__global__ __launch_bounds__(256) void gather3_proj(const int* __restrict__ off,
        const int* __restrict__ srcs, const unsigned* __restrict__ linh3,
        const float* __restrict__ dinv, const float* __restrict__ b3,
        const float* __restrict__ W4, unsigned* __restrict__ linh4, int n) {
    __shared__ float sW4t[8 * 16];
    for (int i = threadIdx.x; i < 16 * 8; i += 256) {
        int k = i >> 3, o = i & 7;
        sW4t[o * 16 + k] = W4[i];
    }
    __syncthreads();
    int g = blockIdx.x * 32 + (threadIdx.x >> 3);
    int f = threadIdx.x & 7;
    if (g >= n) return;
    int rb = off[g], re = off[g + 1];
    unsigned ug = linh3[(size_t)g * 8 + f];
    float a0 = bflo(ug), a1 = bfhi(ug);
    int e = rb;
    for (; e < re && (e & 3); ++e) {
        int s = nt_ld(srcs + e);
        unsigned u = linh3[(size_t)s * 8 + f];
        a0 += bflo(u); a1 += bfhi(u);
    }
    for (; e + 16 <= re; e += 16) {
        i32x4 v0 = nt_ld4(srcs + e),     v1 = nt_ld4(srcs + e + 4);
        i32x4 v2 = nt_ld4(srcs + e + 8), v3 = nt_ld4(srcs + e + 12);
        int ss[16] = { v0[0], v0[1], v0[2], v0[3], v1[0], v1[1], v1[2], v1[3],
                       v2[0], v2[1], v2[2], v2[3], v3[0], v3[1], v3[2], v3[3] };
        unsigned uu[16];
#pragma unroll
        for (int q = 0; q < 16; ++q) uu[q] = linh3[(size_t)ss[q] * 8 + f];
#pragma unroll
        for (int q = 0; q < 16; ++q) { a0 += bflo(uu[q]); a1 += bfhi(uu[q]); }
    }
    for (; e + 4 <= re; e += 4) {
        i32x4 v = nt_ld4(srcs + e);
        int ss[4] = { v[0], v[1], v[2], v[3] };
        unsigned uu[4];
#pragma unroll
        for (int q = 0; q < 4; ++q) uu[q] = linh3[(size_t)ss[q] * 8 + f];
#pragma unroll
        for (int q = 0; q < 4; ++q) { a0 += bflo(uu[q]); a1 += bfhi(uu[q]); }
    }
    for (; e < re; ++e) {
        int s = nt_ld(srcs + e);
        unsigned u = linh3[(size_t)s * 8 + f];
        a0 += bflo(u); a1 += bfhi(u);
    }
    float dv = dinv[g];
    float h0 = tanhf(fmaf(dv, a0, b3[2 * f]));
    float h1 = tanhf(fmaf(dv, a1, b3[2 * f + 1]));
    float p[8];
#pragma unroll
    for (int o = 0; o < 8; ++o)
        p[o] = h0 * sW4t[o * 16 + 2 * f] + h1 * sW4t[o * 16 + 2 * f + 1];
#pragma unroll
    for (int m = 1; m <= 4; m <<= 1)
#pragma unroll
        for (int o = 0; o < 8; ++o) p[o] += __shfl_xor(p[o], m);
    if (f < 4) linh4[(size_t)g * 4 + f] = pack2(dv * p[2 * f], dv * p[2 * f + 1]);
}

// ---- layer-4 gather + tanh (writes hout) + fused classifier ------------------
// 4 lanes per node; 16-deep pipeline.

__global__ __launch_bounds__(256) void gather4_cls(const int* __restrict__ off,
        const int* __restrict__ srcs, const unsigned* __restrict__ linh4,
        const float* __restrict__ dinv, const float* __restrict__ b4,
        float* __restrict__ hout, const float* __restrict__ Wc,
        const float* __restrict__ bc, float* __restrict__ out, int n) {
    int g = blockIdx.x * 64 + (threadIdx.x >> 2);
    int f = threadIdx.x & 3;
    if (g >= n) return;
    int rb = off[g], re = off[g + 1];
    unsigned ug = linh4[(size_t)g * 4 + f];
    float a0 = bflo(ug), a1 = bfhi(ug);
    int e = rb;
    for (; e < re && (e & 3); ++e) {
        int s = nt_ld(srcs + e);
        unsigned u = linh4[(size_t)s * 4 + f];
        a0 += bflo(u); a1 += bfhi(u);
    }
    for (; e + 16 <= re; e += 16) {
        i32x4 v0 = nt_ld4(srcs + e),     v1 = nt_ld4(srcs + e + 4);
        i32x4 v2 = nt_ld4(srcs + e + 8), v3 = nt_ld4(srcs + e + 12);
        int ss[16] = { v0[0], v0[1], v0[2], v0[3], v1[0], v1[1], v1[2], v1[3],
                       v2[0], v2[1], v2[2], v2[3], v3[0], v3[1], v3[2], v3[3] };
        unsigned uu[16];
#pragma unroll
        for (int q = 0; q < 16; ++q) uu[q] = linh4[(size_t)ss[q] * 4 + f];
#pragma unroll
        for (int q = 0; q < 16; ++q) { a0 += bflo(uu[q]); a1 += bfhi(uu[q]); }
    }
    for (; e + 4 <= re; e += 4) {
        i32x4 v = nt_ld4(srcs + e);
        int ss[4] = { v[0], v[1], v[2], v[3] };
        unsigned uu[4];
#pragma unroll
        for (int q = 0; q < 4; ++q) uu[q] = linh4[(size_t)ss[q] * 4 + f];
#pragma unroll
        for (int q = 0; q < 4; ++q) { a0 += bflo(uu[q]); a1 += bfhi(uu[q]); }
    }
    for (; e < re; ++e) {
        int s = nt_ld(srcs + e);
        unsigned u = linh4[(size_t)s * 4 + f];
        a0 += bflo(u); a1 += bfhi(u);
    }
    float dv = dinv[g];
    a0 = tanhf(fmaf(dv, a0, b4[2 * f]));
    a1 = tanhf(fmaf(dv, a1, b4[2 * f + 1]));
    *(float2*)(hout + (size_t)g * 8 + 2 * f) = make_float2(a0, a1);
    float p0 = a0 * Wc[4 * f]     + a1 * Wc[4 * f + 2];
    float p1 = a0 * Wc[4 * f + 1] + a1 * Wc[4 * f + 3];
    p0 += __shfl_xor(p0, 1); p1 += __shfl_xor(p1, 1);
    p0 += __shfl_xor(p0, 2); p1 += __shfl_xor(p1, 2);
    if (f == 0) {
        out[(size_t)g * 2]     = p0 + bc[0];
        out[(size_t)g * 2 + 1] = p1 + bc[1];
    }
}

// ---- launch ------------------------------------------------------------------

static inline char* alignp(char* p) {
    return (char*)(((uintptr_t)p + 15) & ~(uintptr_t)15);
}

extern "C" void kernel_launch(void* const* d_in, const int* in_sizes, int n_in,
                              void* d_out, int out_size, void* d_ws, size_t ws_size,
                              hipStream_t stream) {
    const float* x  = (const float*)d_in[0];
    const int*   ei = (const int*)d_in[1];
    const float* W1 = (const float*)d_in[2];  const float* b1 = (const float*)d_in[3];
    const float* W2 = (const float*)d_in[4];
    const float* b2 = (const float*)d_in[5];
    const float* W3 = (const float*)d_in[6];  const float* b3 = (const float*)d_in[7];
    const float* W4 = (const float*)d_in[8];  const float* b4 = (const float*)d_in[9];
    const float* Wc = (const float*)d_in[10]; const float* bc = (const float*)d_in[11];

    float* out  = (float*)d_out;                      // [N,2]
    float* hout = out + (size_t)2 * N_NODES;          // [N,8]

    const int n = N_NODES;
    const int E = in_sizes[1] / 2;
    const int* src = ei;
    const int* dst = ei + E;

    char* w = (char*)d_ws;
    float*        dinv         = (float*)w;        w = alignp(w + (size_t)n * 4);
    int*          bucketCount  = (int*)w;          w = alignp(w + (size_t)NB * 4);
    int*          bucketOff    = (int*)w;          w = alignp(w + (size_t)(NB + 1) * 4);
    int*          bucketCursor = (int*)w;          w = alignp(w + (size_t)NB * 4);
    int*          off          = (int*)w;          w = alignp(w + (size_t)(n + 1) * 4);
    unsigned int* binned       = (unsigned int*)w; w = alignp(w + (size_t)E * 4);
    int*          srcs         = (int*)w;          w = alignp(w + (size_t)E * 4);
    unsigned int* xm           = (unsigned int*)w; w = alignp(w + (size_t)n * 16 * 4);
    unsigned int* xt           = (unsigned int*)w; w = alignp(w + (size_t)n * 4);
    float*        aggx         = (float*)w;        w = alignp(w + (size_t)n * 34 * 4);
    unsigned int* linh2        = (unsigned int*)w; w = alignp(w + (size_t)n * 16 * 4);
    unsigned int* linh3        = (unsigned int*)w; w = alignp(w + (size_t)n * 8 * 4);
    unsigned int* linh4        = (unsigned int*)w; w = alignp(w + (size_t)n * 4 * 4);

    (void)hipMemsetAsync(bucketCount, 0, NB * sizeof(int), stream);
    bucket_count<<<1024, 256, 0, stream>>>(dst, bucketCount, E);
    bucket_scan<<<1, 512, 0, stream>>>(bucketCount, bucketOff, bucketCursor, E);
    bucket_fill<<<(E + CHUNK - 1) / CHUNK, 256, 0, stream>>>(src, dst, bucketCursor, binned, E);
    node_off_sort<<<NB, 256, 0, stream>>>(binned, bucketOff, off, dinv, srcs, n, E);
    x_pack<<<(n + 255) / 256, 256, 0, stream>>>(x, dinv, xm, xt, n);

    // layer 1 aggregation (input space) -> fused layer1+2 dense -> linh2
    gather_x_bf16<<<(n + 15) / 16, 256, 0, stream>>>(off, srcs, xm, xt, dinv, aggx, n);
    gemm12<<<G12_BLOCKS, 256, 0, stream>>>(aggx, W1, b1, W2, dinv, linh2, n);

    // layer 2 gather + projection to linh3
    gather2_proj<<<(n + 15) / 16, 256, 0, stream>>>(off, srcs, linh2, dinv, b2, W3, linh3, n);

    // layer 3 gather + projection to linh4
    gather3_proj<<<(n + 31) / 32, 256, 0, stream>>>(off, srcs, linh3, dinv, b3, W4, linh4, n);

    // layer 4 gather + classifier
    gather4_cls<<<(n + 63) / 64, 256, 0, stream>>>(off, srcs, linh4, dinv, b4, hout,
                                                   Wc, bc, out, n);
}